// Round 20
// baseline (245.967 us; speedup 1.0000x reference)
//
#include <hip/hip_runtime.h>

#define F_IN 512
#define C_OUT 16

#define TILE 4096        // edges per pass1 block
#define NDB 196          // dst buckets: dst>>9 (512 nodes each)
#define DSH 9
#define CAP2 17664       // dst slab capacity (mean 16327, sd 128 -> +10 sigma)
#define NSB 98           // src buckets: src>>10 (1024 nodes each)
#define CAPS 34816       // src slab capacity (mean 32653, sd 180 -> +12 sigma)

typedef __attribute__((ext_vector_type(8))) short bf16x8;
typedef __attribute__((ext_vector_type(4))) float f32x4;
typedef __attribute__((ext_vector_type(4))) float fx4;
typedef __attribute__((ext_vector_type(8))) unsigned short u16x8;
typedef __attribute__((ext_vector_type(16))) unsigned short u16x16;

__device__ inline unsigned short f2bf(float f) {
    unsigned u = __builtin_bit_cast(unsigned, f);
    u += 0x7FFFu + ((u >> 16) & 1u);   // round-to-nearest-even
    return (unsigned short)(u >> 16);
}
__device__ inline float bf2f(unsigned short u) {
    return __builtin_bit_cast(float, ((unsigned)u) << 16);
}

__device__ inline bf16x8 pack_bf8(fx4 a, fx4 b) {
    bf16x8 r;
    r[0] = (short)f2bf(a.x); r[1] = (short)f2bf(a.y);
    r[2] = (short)f2bf(a.z); r[3] = (short)f2bf(a.w);
    r[4] = (short)f2bf(b.x); r[5] = (short)f2bf(b.y);
    r[6] = (short)f2bf(b.z); r[7] = (short)f2bf(b.w);
    return r;
}

// ---------------- mega: r19 (1:2 interleave, shuffle-scan, cbase, u16 spack) ----------
__global__ __launch_bounds__(256) void mega_kernel(
        const float* __restrict__ x, const float* __restrict__ W, const float* __restrict__ bias_,
        const int* __restrict__ src, const int* __restrict__ dst,
        unsigned* __restrict__ ccursor, unsigned* __restrict__ scursor,
        unsigned* __restrict__ fpack, unsigned short* __restrict__ spack,
        float* __restrict__ h0,
        int E, int N, int p1blk) {
    __shared__ unsigned srt[TILE];          // 16 KB
    __shared__ unsigned char bk2[TILE];     // 4 KB
    __shared__ unsigned hd[NDB], cbased[NDB];
    __shared__ unsigned hs2[NSB], cbases_[NSB];
    __shared__ unsigned wtd[4], wts[4];
    int t = threadIdx.x;
    int r3 = blockIdx.x % 3;
    int q3 = blockIdx.x / 3;

    if (r3 == 0) {
        // ---- partition block q3 ----
        int e0 = q3 * TILE;
        int cnt = min(TILE, E - e0);
        const int* sp = src + e0;
        const int* dp = dst + e0;

        for (int i = t; i < NDB; i += 256) hd[i] = 0;
        if (t < NSB) hs2[t] = 0;
        __syncthreads();

        // ---- sweep A: histograms (int4 loads) ----
        int cnt4 = cnt & ~3;
        for (int i = t * 4; i < cnt4; i += 1024) {
            int4 sv = *(const int4*)(sp + i);
            int4 dv = *(const int4*)(dp + i);
            atomicAdd(&hd[(unsigned)dv.x >> DSH], 1u);
            atomicAdd(&hd[(unsigned)dv.y >> DSH], 1u);
            atomicAdd(&hd[(unsigned)dv.z >> DSH], 1u);
            atomicAdd(&hd[(unsigned)dv.w >> DSH], 1u);
            atomicAdd(&hs2[(unsigned)sv.x >> 10], 1u);
            atomicAdd(&hs2[(unsigned)sv.y >> 10], 1u);
            atomicAdd(&hs2[(unsigned)sv.z >> 10], 1u);
            atomicAdd(&hs2[(unsigned)sv.w >> 10], 1u);
        }
        for (int i = cnt4 + t; i < cnt; i += 256) {
            atomicAdd(&hd[(unsigned)dp[i] >> DSH], 1u);
            atomicAdd(&hs2[(unsigned)sp[i] >> 10], 1u);
        }
        __syncthreads();

        // ---- shuffle-based scans (2 barriers) ----
        unsigned vd = (t < NDB) ? hd[t] : 0u;
        unsigned vs = (t < NSB) ? hs2[t] : 0u;
        unsigned xd = vd, xs = vs;
        for (int o2 = 1; o2 < 64; o2 <<= 1) {
            unsigned yd = __shfl_up(xd, o2, 64);
            unsigned ys = __shfl_up(xs, o2, 64);
            if ((t & 63) >= o2) { xd += yd; xs += ys; }
        }
        if ((t & 63) == 63) { wtd[t >> 6] = xd; wts[t >> 6] = xs; }
        __syncthreads();
        unsigned based = 0, bases = 0;
        for (int k = 0; k < (t >> 6); k++) { based += wtd[k]; bases += wts[k]; }
        unsigned exd = xd + based - vd;   // tile-exclusive base for bin t
        unsigned exs = xs + bases - vs;
        if (t < NDB) {
            unsigned gb = vd ? atomicAdd(&ccursor[t], vd) : 0u;
            cbased[t] = gb - exd;         // global addr = b*CAP2 + cbased[b] + i
            hd[t] = exd;                  // tile-local placement cursor
        }
        if (t < NSB) {
            unsigned gb = vs ? atomicAdd(&scursor[t], vs) : 0u;
            cbases_[t] = gb - exs;
            hs2[t] = exs;
        }
        __syncthreads();

        // ---- sweep B: place dst-sorted into srt ----
        for (int i = t * 4; i < cnt4; i += 1024) {
            int4 sv = *(const int4*)(sp + i);
            int4 dv = *(const int4*)(dp + i);
#define PLACE_D(S, D)                                             \
            {                                                     \
                unsigned s_ = (unsigned)(S), d_ = (unsigned)(D);  \
                unsigned b_ = d_ >> DSH;                          \
                unsigned pos_ = atomicAdd(&hd[b_], 1u);           \
                srt[pos_] = (s_ << DSH) | (d_ & 511u);            \
                bk2[pos_] = (unsigned char)b_;                    \
            }
            PLACE_D(sv.x, dv.x);
            PLACE_D(sv.y, dv.y);
            PLACE_D(sv.z, dv.z);
            PLACE_D(sv.w, dv.w);
        }
        for (int i = cnt4 + t; i < cnt; i += 256) {
            unsigned s_ = (unsigned)sp[i], d_ = (unsigned)dp[i];
            unsigned b_ = d_ >> DSH;
            unsigned pos_ = atomicAdd(&hd[b_], 1u);
            srt[pos_] = (s_ << DSH) | (d_ & 511u);
            bk2[pos_] = (unsigned char)b_;
        }
#undef PLACE_D
        __syncthreads();
        // ---- sweep C: linear, wave-coalesced write-out (1 LDS base read) ----
        for (int i = t; i < cnt; i += 256) {
            unsigned b = bk2[i];
            fpack[(size_t)b * CAP2 + (unsigned)(cbased[b] + (unsigned)i)] = srt[i];
        }
        __syncthreads();
        // ---- sweep B2: place src-sorted into srt ----
        for (int i = t * 4; i < cnt4; i += 1024) {
            int4 sv = *(const int4*)(sp + i);
            unsigned p0 = atomicAdd(&hs2[(unsigned)sv.x >> 10], 1u); srt[p0] = (unsigned)sv.x;
            unsigned p1 = atomicAdd(&hs2[(unsigned)sv.y >> 10], 1u); srt[p1] = (unsigned)sv.y;
            unsigned p2 = atomicAdd(&hs2[(unsigned)sv.z >> 10], 1u); srt[p2] = (unsigned)sv.z;
            unsigned p3 = atomicAdd(&hs2[(unsigned)sv.w >> 10], 1u); srt[p3] = (unsigned)sv.w;
        }
        for (int i = cnt4 + t; i < cnt; i += 256) {
            unsigned s_ = (unsigned)sp[i];
            unsigned pos_ = atomicAdd(&hs2[s_ >> 10], 1u);
            srt[pos_] = s_;
        }
        __syncthreads();
        // ---- sweep C2: linear write-out of src runs (u16 local ids) ----
        for (int i = t; i < cnt; i += 256) {
            unsigned s = srt[i];
            unsigned b = s >> 10;
            spack[(size_t)b * CAPS + (unsigned)(cbases_[b] + (unsigned)i)] =
                (unsigned short)(s & 1023u);
        }
        return;
    }

    // ---- linear block lid = 2*q3 + (r3-1): h0 = x @ W^T + b ----
    int lid = 2 * q3 + (r3 - 1);
    int wave = (lid * 256 + t) >> 6;
    int lane = t & 63;
    int ntiles = N >> 4;
    if (wave >= ntiles) return;

    int row  = lane & 15;
    int kgrp = lane >> 4;

    bf16x8 bfrag[16];
#pragma unroll
    for (int s = 0; s < 16; s++) {
        const float* wp = W + row * F_IN + s * 32 + kgrp * 8;
        fx4 w0 = *(const fx4*)(wp);
        fx4 w1 = *(const fx4*)(wp + 4);
        bfrag[s] = pack_bf8(w0, w1);
    }
    float bias = bias_[row];

    int n0 = wave * 16;
    const float* xrow = x + (size_t)(n0 + row) * F_IN + kgrp * 8;
    f32x4 acc = {0.f, 0.f, 0.f, 0.f};
#pragma unroll
    for (int s = 0; s < 16; s++) {
        fx4 x0 = *(const fx4*)(xrow + s * 32);
        fx4 x1 = *(const fx4*)(xrow + s * 32 + 4);
        bf16x8 a = pack_bf8(x0, x1);
        acc = __builtin_amdgcn_mfma_f32_16x16x32_bf16(a, bfrag[s], acc, 0, 0, 0);
    }
    int c = lane & 15;
#pragma unroll
    for (int q = 0; q < 4; q++) {
        int n = n0 + kgrp * 4 + q;
        h0[n * C_OUT + c] = acc[q] + bias;
    }
}

// ---------------- sortdeg: blocks 0..195 exact-sort one dst slab; 196..293 src-deg ----
__global__ __launch_bounds__(512) void sortdeg_kernel(
        const unsigned* __restrict__ ccursor, const unsigned* __restrict__ fpack,
        unsigned* __restrict__ esort,
        const unsigned* __restrict__ scursor, const unsigned short* __restrict__ spack,
        unsigned* __restrict__ deg_in, unsigned* __restrict__ offsets,
        float* __restrict__ norm_in, float* __restrict__ norm_out,
        const float* __restrict__ h0, unsigned short* __restrict__ hs,
        int N) {
    __shared__ unsigned lds[8 * 512 + 512];   // 18 KB: hw[8][512] + tot[512]
    int t = threadIdx.x;

    if ((int)blockIdx.x < NDB) {
        int cb = blockIdx.x;
        int size = (int)ccursor[cb];
        size_t sbase = (size_t)cb * CAP2;
        const unsigned* in = fpack + sbase;
        unsigned (*hw)[512] = (unsigned (*)[512])lds;
        unsigned* tot = lds + 8 * 512;
        int w = t >> 6;

        for (int i = t; i < 8 * 512; i += 512) lds[i] = 0;
        __syncthreads();
        for (int i = t; i < size; i += 512)
            atomicAdd(&hw[w][in[i] & 511u], 1u);
        __syncthreads();

        unsigned c[8];
        unsigned cnt = 0;
#pragma unroll
        for (int k = 0; k < 8; k++) { c[k] = hw[k][t]; cnt += c[k]; }
        tot[t] = cnt;
        __syncthreads();
        for (int d = 1; d < 512; d <<= 1) {
            unsigned v = (t >= d) ? tot[t - d] : 0u;
            __syncthreads();
            tot[t] += v;
            __syncthreads();
        }
        unsigned excl = tot[t] - cnt;
        unsigned run = excl;
#pragma unroll
        for (int k = 0; k < 8; k++) { unsigned cc = c[k]; hw[k][t] = run; run += cc; }
        int n = cb * 512 + t;
        if (n < N) {
            deg_in[n]  = cnt;
            offsets[n] = (unsigned)sbase + excl;
            norm_in[n] = rsqrtf((float)(cnt > 1u ? cnt : 1u));
        }
        __syncthreads();

        for (int i = t; i < size; i += 512) {
            unsigned p = in[i];
            unsigned pos = atomicAdd(&hw[w][p & 511u], 1u);
            esort[sbase + pos] = p >> DSH;
        }
        return;
    }

    // ---- deg part: u16 src hist (2-per-uint loads) -> norm_out; hs = bf16(h0*no) ----
    int b = blockIdx.x - NDB;
    int size = (int)scursor[b];
    const unsigned short* in = spack + (size_t)b * CAPS;   // CAPS even -> uint-aligned
    unsigned* hist = lds;
    for (int i = t; i < 1024; i += 512) hist[i] = 0;
    __syncthreads();
    int size2 = size & ~1;
    for (int i = t * 2; i < size2; i += 1024) {
        unsigned v = *(const unsigned*)(in + i);
        atomicAdd(&hist[v & 1023u], 1u);
        atomicAdd(&hist[(v >> 16) & 1023u], 1u);
    }
    for (int i = size2 + t; i < size; i += 512) atomicAdd(&hist[in[i]], 1u);
    __syncthreads();
    for (int i = t; i < 1024; i += 512) {
        int n = b * 1024 + i;
        if (n < N) {
            unsigned h = hist[i];
            float no = rsqrtf((float)(h > 1u ? h : 1u));
            norm_out[n] = no;
            const float* hp = h0 + (size_t)n * C_OUT;
            fx4 v0 = *(const fx4*)(hp);
            fx4 v1 = *(const fx4*)(hp + 4);
            fx4 v2 = *(const fx4*)(hp + 8);
            fx4 v3 = *(const fx4*)(hp + 12);
            u16x8 r0, r1;
            r0[0] = f2bf(v0.x * no); r0[1] = f2bf(v0.y * no);
            r0[2] = f2bf(v0.z * no); r0[3] = f2bf(v0.w * no);
            r0[4] = f2bf(v1.x * no); r0[5] = f2bf(v1.y * no);
            r0[6] = f2bf(v1.z * no); r0[7] = f2bf(v1.w * no);
            r1[0] = f2bf(v2.x * no); r1[1] = f2bf(v2.y * no);
            r1[2] = f2bf(v2.z * no); r1[3] = f2bf(v2.w * no);
            r1[4] = f2bf(v3.x * no); r1[5] = f2bf(v3.y * no);
            r1[6] = f2bf(v3.z * no); r1[7] = f2bf(v3.w * no);
            unsigned short* op = hs + (size_t)n * C_OUT;
            *(u16x8*)op = r0;
            *(u16x8*)(op + 8) = r1;
        }
    }
}

// ---------------- propagation: 1 lane/node, u16x16 (32B) gathers ----------------------
// vs r19's 2-lane: halves TA gather requests (6.4M -> 3.2M per prop) and removes the
// duplicate edge-index loads (both lanes read the same uint4 before).
__global__ __launch_bounds__(256) void prop_kernel(
        const unsigned* __restrict__ edge_src, const unsigned* __restrict__ offsets,
        const unsigned* __restrict__ deg_in,
        const unsigned short* __restrict__ hs_in, const float* __restrict__ h0,
        const float* __restrict__ norm_in, const float* __restrict__ norm_out,
        unsigned short* __restrict__ out_bf, float* __restrict__ out_f32,
        int N, int final_iter) {
    int n = blockIdx.x * 256 + threadIdx.x;
    if (n >= N) return;

    unsigned off = offsets[n];
    unsigned dg  = deg_in[n];
    float a[16];
#pragma unroll
    for (int k = 0; k < 16; k++) a[k] = 0.f;

    unsigned j = 0;
    unsigned npeel = (4u - (off & 3u)) & 3u;
    if (npeel > dg) npeel = dg;
    for (; j < npeel; j++) {
        u16x16 v = *(const u16x16*)(hs_in + (size_t)edge_src[off + j] * C_OUT);
#pragma unroll
        for (int k = 0; k < 16; k++) a[k] += bf2f(v[k]);
    }
    for (; j + 4 <= dg; j += 4) {
        uint4 s4 = *(const uint4*)(edge_src + off + j);
        u16x16 v0 = *(const u16x16*)(hs_in + (size_t)s4.x * C_OUT);
        u16x16 v1 = *(const u16x16*)(hs_in + (size_t)s4.y * C_OUT);
        u16x16 v2 = *(const u16x16*)(hs_in + (size_t)s4.z * C_OUT);
        u16x16 v3 = *(const u16x16*)(hs_in + (size_t)s4.w * C_OUT);
#pragma unroll
        for (int k = 0; k < 16; k++)
            a[k] += (bf2f(v0[k]) + bf2f(v1[k])) + (bf2f(v2[k]) + bf2f(v3[k]));
    }
    for (; j < dg; j++) {
        u16x16 v = *(const u16x16*)(hs_in + (size_t)edge_src[off + j] * C_OUT);
#pragma unroll
        for (int k = 0; k < 16; k++) a[k] += bf2f(v[k]);
    }

    float ni = 0.5f * norm_in[n];
    const float* hp = h0 + (size_t)n * C_OUT;
    fx4 hv0 = *(const fx4*)hp;
    fx4 hv1 = *(const fx4*)(hp + 4);
    fx4 hv2 = *(const fx4*)(hp + 8);
    fx4 hv3 = *(const fx4*)(hp + 12);
    float r[16];
#pragma unroll
    for (int k = 0; k < 4; k++) {
        r[k]      = a[k]      * ni + 0.5f * hv0[k];
        r[4 + k]  = a[4 + k]  * ni + 0.5f * hv1[k];
        r[8 + k]  = a[8 + k]  * ni + 0.5f * hv2[k];
        r[12 + k] = a[12 + k] * ni + 0.5f * hv3[k];
    }

    if (final_iter) {
        fx4 o0, o1, o2, o3;
#pragma unroll
        for (int k = 0; k < 4; k++) {
            o0[k] = r[k]; o1[k] = r[4 + k]; o2[k] = r[8 + k]; o3[k] = r[12 + k];
        }
        float* op = out_f32 + (size_t)n * C_OUT;
        *(fx4*)op = o0;
        *(fx4*)(op + 4) = o1;
        *(fx4*)(op + 8) = o2;
        *(fx4*)(op + 12) = o3;
    } else {
        float no = norm_out[n];
        u16x8 q0, q1;
#pragma unroll
        for (int k = 0; k < 8; k++) {
            q0[k] = f2bf(r[k] * no);
            q1[k] = f2bf(r[8 + k] * no);
        }
        unsigned short* op = out_bf + (size_t)n * C_OUT;
        *(u16x8*)op = q0;
        *(u16x8*)(op + 8) = q1;
    }
}

extern "C" void kernel_launch(void* const* d_in, const int* in_sizes, int n_in,
                              void* d_out, int out_size, void* d_ws, size_t ws_size,
                              hipStream_t stream) {
    const float* x = (const float*)d_in[0];
    const float* W = (const float*)d_in[1];
    const float* b = (const float*)d_in[2];
    const int* src = (const int*)d_in[3];
    const int* dst = (const int*)d_in[4];
    int N = in_sizes[0] / F_IN;
    int E = in_sizes[3];
    float* out = (float*)d_out;

    char* ws = (char*)d_ws;
    size_t o = 0;
    auto alloc = [&](size_t bytes) -> void* {
        void* p = ws + o;
        o += (bytes + 255) & ~(size_t)255;
        return p;
    };
    float*    h0   = (float*)alloc((size_t)N * C_OUT * 4);
    unsigned short* hs_a = (unsigned short*)alloc((size_t)N * C_OUT * 2);
    unsigned* fpack = (unsigned*)alloc((size_t)NDB * CAP2 * 4);   // 13.85 MB
    unsigned* esort = (unsigned*)alloc((size_t)NDB * CAP2 * 4);   // 13.85 MB
    unsigned short* spack = (unsigned short*)alloc((size_t)NSB * CAPS * 2);  // 6.8 MB
    unsigned* zeroed  = (unsigned*)alloc((NDB + NSB) * 4);
    unsigned* ccursor = zeroed;
    unsigned* scursor = zeroed + NDB;
    float*    norm_out= (float*)alloc((size_t)N * 4);
    float*    norm_in = (float*)alloc((size_t)N * 4);
    unsigned* offsets = (unsigned*)alloc((size_t)N * 4);
    unsigned* deg_in  = (unsigned*)alloc((size_t)N * 4);
    unsigned short* hs_b = (unsigned short*)out;   // bf16 scratch inside f32 out buffer

    int p1blk = (E + TILE - 1) / TILE;      // 782
    int ntiles = N / 16;
    int linblk = (ntiles + 3) / 4;          // 1563
    int grid = p1blk + linblk;              // 2345 = 3*782 - 1

    hipMemsetAsync(zeroed, 0, (NDB + NSB) * 4, stream);
    mega_kernel<<<grid, 256, 0, stream>>>(x, W, b, src, dst,
                                          ccursor, scursor, fpack, spack,
                                          h0, E, N, p1blk);
    sortdeg_kernel<<<NDB + NSB, 512, 0, stream>>>(ccursor, fpack, esort,
                                                  scursor, spack,
                                                  deg_in, offsets, norm_in, norm_out,
                                                  h0, hs_a, N);

    int pb = (N + 255) / 256;
    prop_kernel<<<pb, 256, 0, stream>>>(esort, offsets, deg_in, hs_a, h0, norm_in, norm_out, hs_b, 0, N, 0);
    prop_kernel<<<pb, 256, 0, stream>>>(esort, offsets, deg_in, hs_b, h0, norm_in, norm_out, hs_a, 0, N, 0);
    prop_kernel<<<pb, 256, 0, stream>>>(esort, offsets, deg_in, hs_a, h0, norm_in, norm_out, 0, out, N, 1);
}

// Round 21
// 234.838 us; speedup vs baseline: 1.0474x; 1.0474x over previous
//
#include <hip/hip_runtime.h>

#define F_IN 512
#define C_OUT 16

#define TILE 4096        // edges per pass1 block
#define NDB 196          // dst buckets: dst>>9 (512 nodes each)
#define DSH 9
#define CAP2 17664       // dst slab capacity (mean 16327, sd 128 -> +10 sigma)
#define NSB 98           // src buckets: src>>10 (1024 nodes each)
#define CAPS 34816       // src slab capacity (mean 32653, sd 180 -> +12 sigma)

typedef __attribute__((ext_vector_type(8))) short bf16x8;
typedef __attribute__((ext_vector_type(4))) float f32x4;
typedef __attribute__((ext_vector_type(4))) float fx4;
typedef __attribute__((ext_vector_type(8))) unsigned short u16x8;

__device__ inline unsigned short f2bf(float f) {
    unsigned u = __builtin_bit_cast(unsigned, f);
    u += 0x7FFFu + ((u >> 16) & 1u);   // round-to-nearest-even
    return (unsigned short)(u >> 16);
}
__device__ inline float bf2f(unsigned short u) {
    return __builtin_bit_cast(float, ((unsigned)u) << 16);
}

__device__ inline bf16x8 pack_bf8(fx4 a, fx4 b) {
    bf16x8 r;
    r[0] = (short)f2bf(a.x); r[1] = (short)f2bf(a.y);
    r[2] = (short)f2bf(a.z); r[3] = (short)f2bf(a.w);
    r[4] = (short)f2bf(b.x); r[5] = (short)f2bf(b.y);
    r[6] = (short)f2bf(b.z); r[7] = (short)f2bf(b.w);
    return r;
}

// ---------------- mega: r19 (1:2 interleave, shuffle-scan, cbase, u16 spack) ----------
__global__ __launch_bounds__(256) void mega_kernel(
        const float* __restrict__ x, const float* __restrict__ W, const float* __restrict__ bias_,
        const int* __restrict__ src, const int* __restrict__ dst,
        unsigned* __restrict__ ccursor, unsigned* __restrict__ scursor,
        unsigned* __restrict__ fpack, unsigned short* __restrict__ spack,
        float* __restrict__ h0,
        int E, int N, int p1blk) {
    __shared__ unsigned srt[TILE];          // 16 KB
    __shared__ unsigned char bk2[TILE];     // 4 KB
    __shared__ unsigned hd[NDB], cbased[NDB];
    __shared__ unsigned hs2[NSB], cbases_[NSB];
    __shared__ unsigned wtd[4], wts[4];
    int t = threadIdx.x;
    int r3 = blockIdx.x % 3;
    int q3 = blockIdx.x / 3;

    if (r3 == 0) {
        // ---- partition block q3 ----
        int e0 = q3 * TILE;
        int cnt = min(TILE, E - e0);
        const int* sp = src + e0;
        const int* dp = dst + e0;

        for (int i = t; i < NDB; i += 256) hd[i] = 0;
        if (t < NSB) hs2[t] = 0;
        __syncthreads();

        // ---- sweep A: histograms (int4 loads) ----
        int cnt4 = cnt & ~3;
        for (int i = t * 4; i < cnt4; i += 1024) {
            int4 sv = *(const int4*)(sp + i);
            int4 dv = *(const int4*)(dp + i);
            atomicAdd(&hd[(unsigned)dv.x >> DSH], 1u);
            atomicAdd(&hd[(unsigned)dv.y >> DSH], 1u);
            atomicAdd(&hd[(unsigned)dv.z >> DSH], 1u);
            atomicAdd(&hd[(unsigned)dv.w >> DSH], 1u);
            atomicAdd(&hs2[(unsigned)sv.x >> 10], 1u);
            atomicAdd(&hs2[(unsigned)sv.y >> 10], 1u);
            atomicAdd(&hs2[(unsigned)sv.z >> 10], 1u);
            atomicAdd(&hs2[(unsigned)sv.w >> 10], 1u);
        }
        for (int i = cnt4 + t; i < cnt; i += 256) {
            atomicAdd(&hd[(unsigned)dp[i] >> DSH], 1u);
            atomicAdd(&hs2[(unsigned)sp[i] >> 10], 1u);
        }
        __syncthreads();

        // ---- shuffle-based scans (2 barriers) ----
        unsigned vd = (t < NDB) ? hd[t] : 0u;
        unsigned vs = (t < NSB) ? hs2[t] : 0u;
        unsigned xd = vd, xs = vs;
        for (int o2 = 1; o2 < 64; o2 <<= 1) {
            unsigned yd = __shfl_up(xd, o2, 64);
            unsigned ys = __shfl_up(xs, o2, 64);
            if ((t & 63) >= o2) { xd += yd; xs += ys; }
        }
        if ((t & 63) == 63) { wtd[t >> 6] = xd; wts[t >> 6] = xs; }
        __syncthreads();
        unsigned based = 0, bases = 0;
        for (int k = 0; k < (t >> 6); k++) { based += wtd[k]; bases += wts[k]; }
        unsigned exd = xd + based - vd;   // tile-exclusive base for bin t
        unsigned exs = xs + bases - vs;
        if (t < NDB) {
            unsigned gb = vd ? atomicAdd(&ccursor[t], vd) : 0u;
            cbased[t] = gb - exd;         // global addr = b*CAP2 + cbased[b] + i
            hd[t] = exd;                  // tile-local placement cursor
        }
        if (t < NSB) {
            unsigned gb = vs ? atomicAdd(&scursor[t], vs) : 0u;
            cbases_[t] = gb - exs;
            hs2[t] = exs;
        }
        __syncthreads();

        // ---- sweep B: place dst-sorted into srt ----
        for (int i = t * 4; i < cnt4; i += 1024) {
            int4 sv = *(const int4*)(sp + i);
            int4 dv = *(const int4*)(dp + i);
#define PLACE_D(S, D)                                             \
            {                                                     \
                unsigned s_ = (unsigned)(S), d_ = (unsigned)(D);  \
                unsigned b_ = d_ >> DSH;                          \
                unsigned pos_ = atomicAdd(&hd[b_], 1u);           \
                srt[pos_] = (s_ << DSH) | (d_ & 511u);            \
                bk2[pos_] = (unsigned char)b_;                    \
            }
            PLACE_D(sv.x, dv.x);
            PLACE_D(sv.y, dv.y);
            PLACE_D(sv.z, dv.z);
            PLACE_D(sv.w, dv.w);
        }
        for (int i = cnt4 + t; i < cnt; i += 256) {
            unsigned s_ = (unsigned)sp[i], d_ = (unsigned)dp[i];
            unsigned b_ = d_ >> DSH;
            unsigned pos_ = atomicAdd(&hd[b_], 1u);
            srt[pos_] = (s_ << DSH) | (d_ & 511u);
            bk2[pos_] = (unsigned char)b_;
        }
#undef PLACE_D
        __syncthreads();
        // ---- sweep C: linear, wave-coalesced write-out (1 LDS base read) ----
        for (int i = t; i < cnt; i += 256) {
            unsigned b = bk2[i];
            fpack[(size_t)b * CAP2 + (unsigned)(cbased[b] + (unsigned)i)] = srt[i];
        }
        __syncthreads();
        // ---- sweep B2: place src-sorted into srt ----
        for (int i = t * 4; i < cnt4; i += 1024) {
            int4 sv = *(const int4*)(sp + i);
            unsigned p0 = atomicAdd(&hs2[(unsigned)sv.x >> 10], 1u); srt[p0] = (unsigned)sv.x;
            unsigned p1 = atomicAdd(&hs2[(unsigned)sv.y >> 10], 1u); srt[p1] = (unsigned)sv.y;
            unsigned p2 = atomicAdd(&hs2[(unsigned)sv.z >> 10], 1u); srt[p2] = (unsigned)sv.z;
            unsigned p3 = atomicAdd(&hs2[(unsigned)sv.w >> 10], 1u); srt[p3] = (unsigned)sv.w;
        }
        for (int i = cnt4 + t; i < cnt; i += 256) {
            unsigned s_ = (unsigned)sp[i];
            unsigned pos_ = atomicAdd(&hs2[s_ >> 10], 1u);
            srt[pos_] = s_;
        }
        __syncthreads();
        // ---- sweep C2: linear write-out of src runs (u16 local ids) ----
        for (int i = t; i < cnt; i += 256) {
            unsigned s = srt[i];
            unsigned b = s >> 10;
            spack[(size_t)b * CAPS + (unsigned)(cbases_[b] + (unsigned)i)] =
                (unsigned short)(s & 1023u);
        }
        return;
    }

    // ---- linear block lid = 2*q3 + (r3-1): h0 = x @ W^T + b ----
    int lid = 2 * q3 + (r3 - 1);
    int wave = (lid * 256 + t) >> 6;
    int lane = t & 63;
    int ntiles = N >> 4;
    if (wave >= ntiles) return;

    int row  = lane & 15;
    int kgrp = lane >> 4;

    bf16x8 bfrag[16];
#pragma unroll
    for (int s = 0; s < 16; s++) {
        const float* wp = W + row * F_IN + s * 32 + kgrp * 8;
        fx4 w0 = *(const fx4*)(wp);
        fx4 w1 = *(const fx4*)(wp + 4);
        bfrag[s] = pack_bf8(w0, w1);
    }
    float bias = bias_[row];

    int n0 = wave * 16;
    const float* xrow = x + (size_t)(n0 + row) * F_IN + kgrp * 8;
    f32x4 acc = {0.f, 0.f, 0.f, 0.f};
#pragma unroll
    for (int s = 0; s < 16; s++) {
        fx4 x0 = *(const fx4*)(xrow + s * 32);
        fx4 x1 = *(const fx4*)(xrow + s * 32 + 4);
        bf16x8 a = pack_bf8(x0, x1);
        acc = __builtin_amdgcn_mfma_f32_16x16x32_bf16(a, bfrag[s], acc, 0, 0, 0);
    }
    int c = lane & 15;
#pragma unroll
    for (int q = 0; q < 4; q++) {
        int n = n0 + kgrp * 4 + q;
        h0[n * C_OUT + c] = acc[q] + bias;
    }
}

// ---------------- sortdeg: dst-slab exact sort + degree-balanced perm; src-deg --------
__global__ __launch_bounds__(512) void sortdeg_kernel(
        const unsigned* __restrict__ ccursor, const unsigned* __restrict__ fpack,
        unsigned* __restrict__ esort, unsigned* __restrict__ perm,
        const unsigned* __restrict__ scursor, const unsigned short* __restrict__ spack,
        unsigned* __restrict__ deg_in, unsigned* __restrict__ offsets,
        float* __restrict__ norm_in, float* __restrict__ norm_out,
        const float* __restrict__ h0, unsigned short* __restrict__ hs,
        int N) {
    __shared__ unsigned lds[8 * 512 + 512];   // 18 KB: hw[8][512] + tot[512]
    __shared__ unsigned h2[128], b2[128];     // degree-permutation hist/scan
    int t = threadIdx.x;

    if ((int)blockIdx.x < NDB) {
        int cb = blockIdx.x;
        int size = (int)ccursor[cb];
        size_t sbase = (size_t)cb * CAP2;
        const unsigned* in = fpack + sbase;
        unsigned (*hw)[512] = (unsigned (*)[512])lds;
        unsigned* tot = lds + 8 * 512;
        int w = t >> 6;

        for (int i = t; i < 8 * 512; i += 512) lds[i] = 0;
        __syncthreads();
        for (int i = t; i < size; i += 512)
            atomicAdd(&hw[w][in[i] & 511u], 1u);
        __syncthreads();

        unsigned c[8];
        unsigned cnt = 0;
#pragma unroll
        for (int k = 0; k < 8; k++) { c[k] = hw[k][t]; cnt += c[k]; }
        tot[t] = cnt;
        __syncthreads();
        for (int d = 1; d < 512; d <<= 1) {
            unsigned v = (t >= d) ? tot[t - d] : 0u;
            __syncthreads();
            tot[t] += v;
            __syncthreads();
        }
        unsigned excl = tot[t] - cnt;
        unsigned run = excl;
#pragma unroll
        for (int k = 0; k < 8; k++) { unsigned cc = c[k]; hw[k][t] = run; run += cc; }
        int n = cb * 512 + t;
        if (n < N) {
            deg_in[n]  = cnt;
            offsets[n] = (unsigned)sbase + excl;
            norm_in[n] = rsqrtf((float)(cnt > 1u ? cnt : 1u));
        }
        if (t < 128) h2[t] = 0;
        __syncthreads();

        // esort scatter + degree histogram (independent LDS arrays, same phase)
        unsigned dcl = cnt > 127u ? 127u : cnt;
        if (n < N) atomicAdd(&h2[dcl], 1u);
        for (int i = t; i < size; i += 512) {
            unsigned p = in[i];
            unsigned pos = atomicAdd(&hw[w][p & 511u], 1u);
            esort[sbase + pos] = p >> DSH;
        }
        __syncthreads();

        // scan degree hist -> cursors; emit degree-sorted node permutation
        if (t < 128) b2[t] = h2[t];
        __syncthreads();
        for (int d = 1; d < 128; d <<= 1) {
            unsigned v = (t < 128 && t >= d) ? b2[t - d] : 0u;
            __syncthreads();
            if (t < 128) b2[t] += v;
            __syncthreads();
        }
        if (t < 128) h2[t] = b2[t] - h2[t];   // exclusive base -> cursor
        __syncthreads();
        if (n < N) {
            unsigned pos = atomicAdd(&h2[dcl], 1u);
            perm[cb * 512 + pos] = (unsigned)n;
        }
        return;
    }

    // ---- deg part: u16 src hist (2-per-uint loads) -> norm_out; hs = bf16(h0*no) ----
    int b = blockIdx.x - NDB;
    int size = (int)scursor[b];
    const unsigned short* in = spack + (size_t)b * CAPS;   // CAPS even -> uint-aligned
    unsigned* hist = lds;
    for (int i = t; i < 1024; i += 512) hist[i] = 0;
    __syncthreads();
    int size2 = size & ~1;
    for (int i = t * 2; i < size2; i += 1024) {
        unsigned v = *(const unsigned*)(in + i);
        atomicAdd(&hist[v & 1023u], 1u);
        atomicAdd(&hist[(v >> 16) & 1023u], 1u);
    }
    for (int i = size2 + t; i < size; i += 512) atomicAdd(&hist[in[i]], 1u);
    __syncthreads();
    for (int i = t; i < 1024; i += 512) {
        int n = b * 1024 + i;
        if (n < N) {
            unsigned h = hist[i];
            float no = rsqrtf((float)(h > 1u ? h : 1u));
            norm_out[n] = no;
            const float* hp = h0 + (size_t)n * C_OUT;
            fx4 v0 = *(const fx4*)(hp);
            fx4 v1 = *(const fx4*)(hp + 4);
            fx4 v2 = *(const fx4*)(hp + 8);
            fx4 v3 = *(const fx4*)(hp + 12);
            u16x8 r0, r1;
            r0[0] = f2bf(v0.x * no); r0[1] = f2bf(v0.y * no);
            r0[2] = f2bf(v0.z * no); r0[3] = f2bf(v0.w * no);
            r0[4] = f2bf(v1.x * no); r0[5] = f2bf(v1.y * no);
            r0[6] = f2bf(v1.z * no); r0[7] = f2bf(v1.w * no);
            r1[0] = f2bf(v2.x * no); r1[1] = f2bf(v2.y * no);
            r1[2] = f2bf(v2.z * no); r1[3] = f2bf(v2.w * no);
            r1[4] = f2bf(v3.x * no); r1[5] = f2bf(v3.y * no);
            r1[6] = f2bf(v3.z * no); r1[7] = f2bf(v3.w * no);
            unsigned short* op = hs + (size_t)n * C_OUT;
            *(u16x8*)op = r0;
            *(u16x8*)(op + 8) = r1;
        }
    }
}

// ---------------- propagation: perm-indexed (degree-balanced waves), 2 lanes/node -----
__global__ __launch_bounds__(256) void prop_kernel(
        const unsigned* __restrict__ perm,
        const unsigned* __restrict__ edge_src, const unsigned* __restrict__ offsets,
        const unsigned* __restrict__ deg_in,
        const unsigned short* __restrict__ hs_in, const float* __restrict__ h0,
        const float* __restrict__ norm_in, const float* __restrict__ norm_out,
        unsigned short* __restrict__ out_bf, float* __restrict__ out_f32,
        int N, int final_iter) {
    int t = threadIdx.x;
    int i0 = blockIdx.x * 128 + (t >> 1);
    if (i0 >= N) return;
    int n = (int)perm[i0];
    int q = t & 1;                       // channel half: channels 8q..8q+7

    unsigned off = offsets[n];
    unsigned dg  = deg_in[n];
    const unsigned short* hp = hs_in + q * 8;
    float a[8];
#pragma unroll
    for (int k = 0; k < 8; k++) a[k] = 0.f;

    unsigned j = 0;
    unsigned npeel = (4u - (off & 3u)) & 3u;
    if (npeel > dg) npeel = dg;
    for (; j < npeel; j++) {
        u16x8 u0 = *(const u16x8*)(hp + edge_src[off + j] * C_OUT);
#pragma unroll
        for (int k = 0; k < 8; k++) a[k] += bf2f(u0[k]);
    }
    for (; j + 4 <= dg; j += 4) {
        uint4 s4 = *(const uint4*)(edge_src + off + j);
        u16x8 u0 = *(const u16x8*)(hp + s4.x * C_OUT);
        u16x8 u1 = *(const u16x8*)(hp + s4.y * C_OUT);
        u16x8 u2 = *(const u16x8*)(hp + s4.z * C_OUT);
        u16x8 u3 = *(const u16x8*)(hp + s4.w * C_OUT);
#pragma unroll
        for (int k = 0; k < 8; k++)
            a[k] += (bf2f(u0[k]) + bf2f(u1[k])) + (bf2f(u2[k]) + bf2f(u3[k]));
    }
    for (; j < dg; j++) {
        u16x8 u0 = *(const u16x8*)(hp + edge_src[off + j] * C_OUT);
#pragma unroll
        for (int k = 0; k < 8; k++) a[k] += bf2f(u0[k]);
    }

    float ni = 0.5f * norm_in[n];
    const float* h0p = h0 + n * C_OUT + q * 8;
    fx4 hva = *(const fx4*)h0p;
    fx4 hvb = *(const fx4*)(h0p + 4);
    float r[8];
    r[0] = a[0] * ni + 0.5f * hva.x;
    r[1] = a[1] * ni + 0.5f * hva.y;
    r[2] = a[2] * ni + 0.5f * hva.z;
    r[3] = a[3] * ni + 0.5f * hva.w;
    r[4] = a[4] * ni + 0.5f * hvb.x;
    r[5] = a[5] * ni + 0.5f * hvb.y;
    r[6] = a[6] * ni + 0.5f * hvb.z;
    r[7] = a[7] * ni + 0.5f * hvb.w;

    if (final_iter) {
        fx4 ra = {r[0], r[1], r[2], r[3]};
        fx4 rb = {r[4], r[5], r[6], r[7]};
        float* op = out_f32 + n * C_OUT + q * 8;
        *(fx4*)op = ra;
        *(fx4*)(op + 4) = rb;
    } else {
        float no = norm_out[n];
        u16x8 res;
#pragma unroll
        for (int k = 0; k < 8; k++) res[k] = f2bf(r[k] * no);
        *(u16x8*)(out_bf + n * C_OUT + q * 8) = res;
    }
}

extern "C" void kernel_launch(void* const* d_in, const int* in_sizes, int n_in,
                              void* d_out, int out_size, void* d_ws, size_t ws_size,
                              hipStream_t stream) {
    const float* x = (const float*)d_in[0];
    const float* W = (const float*)d_in[1];
    const float* b = (const float*)d_in[2];
    const int* src = (const int*)d_in[3];
    const int* dst = (const int*)d_in[4];
    int N = in_sizes[0] / F_IN;
    int E = in_sizes[3];
    float* out = (float*)d_out;

    char* ws = (char*)d_ws;
    size_t o = 0;
    auto alloc = [&](size_t bytes) -> void* {
        void* p = ws + o;
        o += (bytes + 255) & ~(size_t)255;
        return p;
    };
    float*    h0   = (float*)alloc((size_t)N * C_OUT * 4);
    unsigned short* hs_a = (unsigned short*)alloc((size_t)N * C_OUT * 2);
    unsigned* fpack = (unsigned*)alloc((size_t)NDB * CAP2 * 4);   // 13.85 MB
    unsigned* esort = (unsigned*)alloc((size_t)NDB * CAP2 * 4);   // 13.85 MB
    unsigned short* spack = (unsigned short*)alloc((size_t)NSB * CAPS * 2);  // 6.8 MB
    unsigned* perm  = (unsigned*)alloc((size_t)NDB * 512 * 4);
    unsigned* zeroed  = (unsigned*)alloc((NDB + NSB) * 4);
    unsigned* ccursor = zeroed;
    unsigned* scursor = zeroed + NDB;
    float*    norm_out= (float*)alloc((size_t)N * 4);
    float*    norm_in = (float*)alloc((size_t)N * 4);
    unsigned* offsets = (unsigned*)alloc((size_t)N * 4);
    unsigned* deg_in  = (unsigned*)alloc((size_t)N * 4);
    unsigned short* hs_b = (unsigned short*)out;   // bf16 scratch inside f32 out buffer

    int p1blk = (E + TILE - 1) / TILE;      // 782
    int ntiles = N / 16;
    int linblk = (ntiles + 3) / 4;          // 1563
    int grid = p1blk + linblk;              // 2345 = 3*782 - 1

    hipMemsetAsync(zeroed, 0, (NDB + NSB) * 4, stream);
    mega_kernel<<<grid, 256, 0, stream>>>(x, W, b, src, dst,
                                          ccursor, scursor, fpack, spack,
                                          h0, E, N, p1blk);
    sortdeg_kernel<<<NDB + NSB, 512, 0, stream>>>(ccursor, fpack, esort, perm,
                                                  scursor, spack,
                                                  deg_in, offsets, norm_in, norm_out,
                                                  h0, hs_a, N);

    int pb = (N + 127) / 128;
    prop_kernel<<<pb, 256, 0, stream>>>(perm, esort, offsets, deg_in, hs_a, h0, norm_in, norm_out, hs_b, 0, N, 0);
    prop_kernel<<<pb, 256, 0, stream>>>(perm, esort, offsets, deg_in, hs_b, h0, norm_in, norm_out, hs_a, 0, N, 0);
    prop_kernel<<<pb, 256, 0, stream>>>(perm, esort, offsets, deg_in, hs_a, h0, norm_in, norm_out, 0, out, N, 1);
}

// Round 22
// 213.944 us; speedup vs baseline: 1.1497x; 1.0977x over previous
//
#include <hip/hip_runtime.h>

#define F_IN 512
#define C_OUT 16

#define TILE 4096        // edges per pass1 block
#define NDB 196          // dst buckets: dst>>9 (512 nodes each)
#define DSH 9
#define CAP2 17664       // dst slab capacity (mean 16327, sd 128 -> +10 sigma)
#define NSB 98           // src buckets: src>>10 (1024 nodes each)
#define CAPS 34816       // src slab capacity (mean 32653, sd 180 -> +12 sigma)

typedef __attribute__((ext_vector_type(8))) short bf16x8;
typedef __attribute__((ext_vector_type(4))) float f32x4;
typedef __attribute__((ext_vector_type(4))) float fx4;
typedef __attribute__((ext_vector_type(8))) unsigned short u16x8;

__device__ inline unsigned short f2bf(float f) {
    unsigned u = __builtin_bit_cast(unsigned, f);
    u += 0x7FFFu + ((u >> 16) & 1u);   // round-to-nearest-even
    return (unsigned short)(u >> 16);
}
__device__ inline float bf2f(unsigned short u) {
    return __builtin_bit_cast(float, ((unsigned)u) << 16);
}

__device__ inline bf16x8 pack_bf8(fx4 a, fx4 b) {
    bf16x8 r;
    r[0] = (short)f2bf(a.x); r[1] = (short)f2bf(a.y);
    r[2] = (short)f2bf(a.z); r[3] = (short)f2bf(a.w);
    r[4] = (short)f2bf(b.x); r[5] = (short)f2bf(b.y);
    r[6] = (short)f2bf(b.z); r[7] = (short)f2bf(b.w);
    return r;
}

// ---------------- mega: r19 final (1:2 interleave, shuffle-scan, cbase, u16 spack) ----
// Session-final structure. Key verified mechanisms:
//  - LDS counting-sort + linear write-out (r12): cursor-scatter stores never
//    wave-coalesce (~3.5x write amp regardless of bucket count); sorted-tile linear
//    stores fixed WRITE_SIZE 112->32 MB.
//  - role = bid%3 interleave (r17): blocks dispatch ~in blockIdx order, so fusion
//    without interleave = concatenation. Interleave gives true pass1||linear overlap.
//  - shuffle scans + combined write-bases (r19): fewer barriers/LDS reads in pass1.
// Dead ends (measured): nt loads (r10 +22), finer/coarser buckets (r7/r8), per-wave
// hist replication (r13 0), TILE=2048 (r15 +33), atomic-free segment layout (r16 +62),
// 1:1 ratio (r18 +3), 1-lane prop (r20 +31), degree-balanced perm (r21 +19).
__global__ __launch_bounds__(256) void mega_kernel(
        const float* __restrict__ x, const float* __restrict__ W, const float* __restrict__ bias_,
        const int* __restrict__ src, const int* __restrict__ dst,
        unsigned* __restrict__ ccursor, unsigned* __restrict__ scursor,
        unsigned* __restrict__ fpack, unsigned short* __restrict__ spack,
        float* __restrict__ h0,
        int E, int N, int p1blk) {
    __shared__ unsigned srt[TILE];          // 16 KB
    __shared__ unsigned char bk2[TILE];     // 4 KB
    __shared__ unsigned hd[NDB], cbased[NDB];
    __shared__ unsigned hs2[NSB], cbases_[NSB];
    __shared__ unsigned wtd[4], wts[4];
    int t = threadIdx.x;
    int r3 = blockIdx.x % 3;
    int q3 = blockIdx.x / 3;

    if (r3 == 0) {
        // ---- partition block q3 ----
        int e0 = q3 * TILE;
        int cnt = min(TILE, E - e0);
        const int* sp = src + e0;
        const int* dp = dst + e0;

        for (int i = t; i < NDB; i += 256) hd[i] = 0;
        if (t < NSB) hs2[t] = 0;
        __syncthreads();

        // ---- sweep A: histograms (int4 loads) ----
        int cnt4 = cnt & ~3;
        for (int i = t * 4; i < cnt4; i += 1024) {
            int4 sv = *(const int4*)(sp + i);
            int4 dv = *(const int4*)(dp + i);
            atomicAdd(&hd[(unsigned)dv.x >> DSH], 1u);
            atomicAdd(&hd[(unsigned)dv.y >> DSH], 1u);
            atomicAdd(&hd[(unsigned)dv.z >> DSH], 1u);
            atomicAdd(&hd[(unsigned)dv.w >> DSH], 1u);
            atomicAdd(&hs2[(unsigned)sv.x >> 10], 1u);
            atomicAdd(&hs2[(unsigned)sv.y >> 10], 1u);
            atomicAdd(&hs2[(unsigned)sv.z >> 10], 1u);
            atomicAdd(&hs2[(unsigned)sv.w >> 10], 1u);
        }
        for (int i = cnt4 + t; i < cnt; i += 256) {
            atomicAdd(&hd[(unsigned)dp[i] >> DSH], 1u);
            atomicAdd(&hs2[(unsigned)sp[i] >> 10], 1u);
        }
        __syncthreads();

        // ---- shuffle-based scans (2 barriers) ----
        unsigned vd = (t < NDB) ? hd[t] : 0u;
        unsigned vs = (t < NSB) ? hs2[t] : 0u;
        unsigned xd = vd, xs = vs;
        for (int o2 = 1; o2 < 64; o2 <<= 1) {
            unsigned yd = __shfl_up(xd, o2, 64);
            unsigned ys = __shfl_up(xs, o2, 64);
            if ((t & 63) >= o2) { xd += yd; xs += ys; }
        }
        if ((t & 63) == 63) { wtd[t >> 6] = xd; wts[t >> 6] = xs; }
        __syncthreads();
        unsigned based = 0, bases = 0;
        for (int k = 0; k < (t >> 6); k++) { based += wtd[k]; bases += wts[k]; }
        unsigned exd = xd + based - vd;   // tile-exclusive base for bin t
        unsigned exs = xs + bases - vs;
        if (t < NDB) {
            unsigned gb = vd ? atomicAdd(&ccursor[t], vd) : 0u;
            cbased[t] = gb - exd;         // global addr = b*CAP2 + cbased[b] + i
            hd[t] = exd;                  // tile-local placement cursor
        }
        if (t < NSB) {
            unsigned gb = vs ? atomicAdd(&scursor[t], vs) : 0u;
            cbases_[t] = gb - exs;
            hs2[t] = exs;
        }
        __syncthreads();

        // ---- sweep B: place dst-sorted into srt ----
        for (int i = t * 4; i < cnt4; i += 1024) {
            int4 sv = *(const int4*)(sp + i);
            int4 dv = *(const int4*)(dp + i);
#define PLACE_D(S, D)                                             \
            {                                                     \
                unsigned s_ = (unsigned)(S), d_ = (unsigned)(D);  \
                unsigned b_ = d_ >> DSH;                          \
                unsigned pos_ = atomicAdd(&hd[b_], 1u);           \
                srt[pos_] = (s_ << DSH) | (d_ & 511u);            \
                bk2[pos_] = (unsigned char)b_;                    \
            }
            PLACE_D(sv.x, dv.x);
            PLACE_D(sv.y, dv.y);
            PLACE_D(sv.z, dv.z);
            PLACE_D(sv.w, dv.w);
        }
        for (int i = cnt4 + t; i < cnt; i += 256) {
            unsigned s_ = (unsigned)sp[i], d_ = (unsigned)dp[i];
            unsigned b_ = d_ >> DSH;
            unsigned pos_ = atomicAdd(&hd[b_], 1u);
            srt[pos_] = (s_ << DSH) | (d_ & 511u);
            bk2[pos_] = (unsigned char)b_;
        }
#undef PLACE_D
        __syncthreads();
        // ---- sweep C: linear, wave-coalesced write-out (1 LDS base read) ----
        for (int i = t; i < cnt; i += 256) {
            unsigned b = bk2[i];
            fpack[(size_t)b * CAP2 + (unsigned)(cbased[b] + (unsigned)i)] = srt[i];
        }
        __syncthreads();
        // ---- sweep B2: place src-sorted into srt ----
        for (int i = t * 4; i < cnt4; i += 1024) {
            int4 sv = *(const int4*)(sp + i);
            unsigned p0 = atomicAdd(&hs2[(unsigned)sv.x >> 10], 1u); srt[p0] = (unsigned)sv.x;
            unsigned p1 = atomicAdd(&hs2[(unsigned)sv.y >> 10], 1u); srt[p1] = (unsigned)sv.y;
            unsigned p2 = atomicAdd(&hs2[(unsigned)sv.z >> 10], 1u); srt[p2] = (unsigned)sv.z;
            unsigned p3 = atomicAdd(&hs2[(unsigned)sv.w >> 10], 1u); srt[p3] = (unsigned)sv.w;
        }
        for (int i = cnt4 + t; i < cnt; i += 256) {
            unsigned s_ = (unsigned)sp[i];
            unsigned pos_ = atomicAdd(&hs2[s_ >> 10], 1u);
            srt[pos_] = s_;
        }
        __syncthreads();
        // ---- sweep C2: linear write-out of src runs (u16 local ids) ----
        for (int i = t; i < cnt; i += 256) {
            unsigned s = srt[i];
            unsigned b = s >> 10;
            spack[(size_t)b * CAPS + (unsigned)(cbases_[b] + (unsigned)i)] =
                (unsigned short)(s & 1023u);
        }
        return;
    }

    // ---- linear block lid = 2*q3 + (r3-1): h0 = x @ W^T + b ----
    int lid = 2 * q3 + (r3 - 1);
    int wave = (lid * 256 + t) >> 6;
    int lane = t & 63;
    int ntiles = N >> 4;
    if (wave >= ntiles) return;

    int row  = lane & 15;
    int kgrp = lane >> 4;

    bf16x8 bfrag[16];
#pragma unroll
    for (int s = 0; s < 16; s++) {
        const float* wp = W + row * F_IN + s * 32 + kgrp * 8;
        fx4 w0 = *(const fx4*)(wp);
        fx4 w1 = *(const fx4*)(wp + 4);
        bfrag[s] = pack_bf8(w0, w1);
    }
    float bias = bias_[row];

    int n0 = wave * 16;
    const float* xrow = x + (size_t)(n0 + row) * F_IN + kgrp * 8;
    f32x4 acc = {0.f, 0.f, 0.f, 0.f};
#pragma unroll
    for (int s = 0; s < 16; s++) {
        fx4 x0 = *(const fx4*)(xrow + s * 32);
        fx4 x1 = *(const fx4*)(xrow + s * 32 + 4);
        bf16x8 a = pack_bf8(x0, x1);
        acc = __builtin_amdgcn_mfma_f32_16x16x32_bf16(a, bfrag[s], acc, 0, 0, 0);
    }
    int c = lane & 15;
#pragma unroll
    for (int q = 0; q < 4; q++) {
        int n = n0 + kgrp * 4 + q;
        h0[n * C_OUT + c] = acc[q] + bias;
    }
}

// ---------------- sortdeg: blocks 0..195 exact-sort one dst slab; 196..293 src-deg ----
__global__ __launch_bounds__(512) void sortdeg_kernel(
        const unsigned* __restrict__ ccursor, const unsigned* __restrict__ fpack,
        unsigned* __restrict__ esort,
        const unsigned* __restrict__ scursor, const unsigned short* __restrict__ spack,
        unsigned* __restrict__ deg_in, unsigned* __restrict__ offsets,
        float* __restrict__ norm_in, float* __restrict__ norm_out,
        const float* __restrict__ h0, unsigned short* __restrict__ hs,
        int N) {
    __shared__ unsigned lds[8 * 512 + 512];   // 18 KB: hw[8][512] + tot[512]
    int t = threadIdx.x;

    if ((int)blockIdx.x < NDB) {
        int cb = blockIdx.x;
        int size = (int)ccursor[cb];
        size_t sbase = (size_t)cb * CAP2;
        const unsigned* in = fpack + sbase;
        unsigned (*hw)[512] = (unsigned (*)[512])lds;
        unsigned* tot = lds + 8 * 512;
        int w = t >> 6;

        for (int i = t; i < 8 * 512; i += 512) lds[i] = 0;
        __syncthreads();
        for (int i = t; i < size; i += 512)
            atomicAdd(&hw[w][in[i] & 511u], 1u);
        __syncthreads();

        unsigned c[8];
        unsigned cnt = 0;
#pragma unroll
        for (int k = 0; k < 8; k++) { c[k] = hw[k][t]; cnt += c[k]; }
        tot[t] = cnt;
        __syncthreads();
        for (int d = 1; d < 512; d <<= 1) {
            unsigned v = (t >= d) ? tot[t - d] : 0u;
            __syncthreads();
            tot[t] += v;
            __syncthreads();
        }
        unsigned excl = tot[t] - cnt;
        unsigned run = excl;
#pragma unroll
        for (int k = 0; k < 8; k++) { unsigned cc = c[k]; hw[k][t] = run; run += cc; }
        int n = cb * 512 + t;
        if (n < N) {
            deg_in[n]  = cnt;
            offsets[n] = (unsigned)sbase + excl;
            norm_in[n] = rsqrtf((float)(cnt > 1u ? cnt : 1u));
        }
        __syncthreads();

        for (int i = t; i < size; i += 512) {
            unsigned p = in[i];
            unsigned pos = atomicAdd(&hw[w][p & 511u], 1u);
            esort[sbase + pos] = p >> DSH;
        }
        return;
    }

    // ---- deg part: u16 src hist (2-per-uint loads) -> norm_out; hs = bf16(h0*no) ----
    int b = blockIdx.x - NDB;
    int size = (int)scursor[b];
    const unsigned short* in = spack + (size_t)b * CAPS;   // CAPS even -> uint-aligned
    unsigned* hist = lds;
    for (int i = t; i < 1024; i += 512) hist[i] = 0;
    __syncthreads();
    int size2 = size & ~1;
    for (int i = t * 2; i < size2; i += 1024) {
        unsigned v = *(const unsigned*)(in + i);
        atomicAdd(&hist[v & 1023u], 1u);
        atomicAdd(&hist[(v >> 16) & 1023u], 1u);
    }
    for (int i = size2 + t; i < size; i += 512) atomicAdd(&hist[in[i]], 1u);
    __syncthreads();
    for (int i = t; i < 1024; i += 512) {
        int n = b * 1024 + i;
        if (n < N) {
            unsigned h = hist[i];
            float no = rsqrtf((float)(h > 1u ? h : 1u));
            norm_out[n] = no;
            const float* hp = h0 + (size_t)n * C_OUT;
            fx4 v0 = *(const fx4*)(hp);
            fx4 v1 = *(const fx4*)(hp + 4);
            fx4 v2 = *(const fx4*)(hp + 8);
            fx4 v3 = *(const fx4*)(hp + 12);
            u16x8 r0, r1;
            r0[0] = f2bf(v0.x * no); r0[1] = f2bf(v0.y * no);
            r0[2] = f2bf(v0.z * no); r0[3] = f2bf(v0.w * no);
            r0[4] = f2bf(v1.x * no); r0[5] = f2bf(v1.y * no);
            r0[6] = f2bf(v1.z * no); r0[7] = f2bf(v1.w * no);
            r1[0] = f2bf(v2.x * no); r1[1] = f2bf(v2.y * no);
            r1[2] = f2bf(v2.z * no); r1[3] = f2bf(v2.w * no);
            r1[4] = f2bf(v3.x * no); r1[5] = f2bf(v3.y * no);
            r1[6] = f2bf(v3.z * no); r1[7] = f2bf(v3.w * no);
            unsigned short* op = hs + (size_t)n * C_OUT;
            *(u16x8*)op = r0;
            *(u16x8*)(op + 8) = r1;
        }
    }
}

// ---------------- propagation: 2 lanes/node, uint4 index loads, u16x8 gathers ---------
__global__ __launch_bounds__(256) void prop_kernel(
        const unsigned* __restrict__ edge_src, const unsigned* __restrict__ offsets,
        const unsigned* __restrict__ deg_in,
        const unsigned short* __restrict__ hs_in, const float* __restrict__ h0,
        const float* __restrict__ norm_in, const float* __restrict__ norm_out,
        unsigned short* __restrict__ out_bf, float* __restrict__ out_f32,
        int N, int final_iter) {
    int t = threadIdx.x;
    int n = blockIdx.x * 128 + (t >> 1);
    if (n >= N) return;
    int q = t & 1;                       // channel half: channels 8q..8q+7

    unsigned off = offsets[n];
    unsigned dg  = deg_in[n];
    const unsigned short* hp = hs_in + q * 8;
    float a[8];
#pragma unroll
    for (int k = 0; k < 8; k++) a[k] = 0.f;

    unsigned j = 0;
    unsigned npeel = (4u - (off & 3u)) & 3u;
    if (npeel > dg) npeel = dg;
    for (; j < npeel; j++) {
        u16x8 u0 = *(const u16x8*)(hp + edge_src[off + j] * C_OUT);
#pragma unroll
        for (int k = 0; k < 8; k++) a[k] += bf2f(u0[k]);
    }
    for (; j + 4 <= dg; j += 4) {
        uint4 s4 = *(const uint4*)(edge_src + off + j);
        u16x8 u0 = *(const u16x8*)(hp + s4.x * C_OUT);
        u16x8 u1 = *(const u16x8*)(hp + s4.y * C_OUT);
        u16x8 u2 = *(const u16x8*)(hp + s4.z * C_OUT);
        u16x8 u3 = *(const u16x8*)(hp + s4.w * C_OUT);
#pragma unroll
        for (int k = 0; k < 8; k++)
            a[k] += (bf2f(u0[k]) + bf2f(u1[k])) + (bf2f(u2[k]) + bf2f(u3[k]));
    }
    for (; j < dg; j++) {
        u16x8 u0 = *(const u16x8*)(hp + edge_src[off + j] * C_OUT);
#pragma unroll
        for (int k = 0; k < 8; k++) a[k] += bf2f(u0[k]);
    }

    float ni = 0.5f * norm_in[n];
    const float* h0p = h0 + n * C_OUT + q * 8;
    fx4 hva = *(const fx4*)h0p;
    fx4 hvb = *(const fx4*)(h0p + 4);
    float r[8];
    r[0] = a[0] * ni + 0.5f * hva.x;
    r[1] = a[1] * ni + 0.5f * hva.y;
    r[2] = a[2] * ni + 0.5f * hva.z;
    r[3] = a[3] * ni + 0.5f * hva.w;
    r[4] = a[4] * ni + 0.5f * hvb.x;
    r[5] = a[5] * ni + 0.5f * hvb.y;
    r[6] = a[6] * ni + 0.5f * hvb.z;
    r[7] = a[7] * ni + 0.5f * hvb.w;

    if (final_iter) {
        fx4 ra = {r[0], r[1], r[2], r[3]};
        fx4 rb = {r[4], r[5], r[6], r[7]};
        float* op = out_f32 + n * C_OUT + q * 8;
        *(fx4*)op = ra;
        *(fx4*)(op + 4) = rb;
    } else {
        float no = norm_out[n];
        u16x8 res;
#pragma unroll
        for (int k = 0; k < 8; k++) res[k] = f2bf(r[k] * no);
        *(u16x8*)(out_bf + n * C_OUT + q * 8) = res;
    }
}

extern "C" void kernel_launch(void* const* d_in, const int* in_sizes, int n_in,
                              void* d_out, int out_size, void* d_ws, size_t ws_size,
                              hipStream_t stream) {
    const float* x = (const float*)d_in[0];
    const float* W = (const float*)d_in[1];
    const float* b = (const float*)d_in[2];
    const int* src = (const int*)d_in[3];
    const int* dst = (const int*)d_in[4];
    int N = in_sizes[0] / F_IN;
    int E = in_sizes[3];
    float* out = (float*)d_out;

    char* ws = (char*)d_ws;
    size_t o = 0;
    auto alloc = [&](size_t bytes) -> void* {
        void* p = ws + o;
        o += (bytes + 255) & ~(size_t)255;
        return p;
    };
    float*    h0   = (float*)alloc((size_t)N * C_OUT * 4);
    unsigned short* hs_a = (unsigned short*)alloc((size_t)N * C_OUT * 2);
    unsigned* fpack = (unsigned*)alloc((size_t)NDB * CAP2 * 4);   // 13.85 MB
    unsigned* esort = (unsigned*)alloc((size_t)NDB * CAP2 * 4);   // 13.85 MB
    unsigned short* spack = (unsigned short*)alloc((size_t)NSB * CAPS * 2);  // 6.8 MB
    unsigned* zeroed  = (unsigned*)alloc((NDB + NSB) * 4);
    unsigned* ccursor = zeroed;
    unsigned* scursor = zeroed + NDB;
    float*    norm_out= (float*)alloc((size_t)N * 4);
    float*    norm_in = (float*)alloc((size_t)N * 4);
    unsigned* offsets = (unsigned*)alloc((size_t)N * 4);
    unsigned* deg_in  = (unsigned*)alloc((size_t)N * 4);
    unsigned short* hs_b = (unsigned short*)out;   // bf16 scratch inside f32 out buffer

    int p1blk = (E + TILE - 1) / TILE;      // 782
    int ntiles = N / 16;
    int linblk = (ntiles + 3) / 4;          // 1563
    int grid = p1blk + linblk;              // 2345 = 3*782 - 1

    hipMemsetAsync(zeroed, 0, (NDB + NSB) * 4, stream);
    mega_kernel<<<grid, 256, 0, stream>>>(x, W, b, src, dst,
                                          ccursor, scursor, fpack, spack,
                                          h0, E, N, p1blk);
    sortdeg_kernel<<<NDB + NSB, 512, 0, stream>>>(ccursor, fpack, esort,
                                                  scursor, spack,
                                                  deg_in, offsets, norm_in, norm_out,
                                                  h0, hs_a, N);

    int pb = (N + 127) / 128;
    prop_kernel<<<pb, 256, 0, stream>>>(esort, offsets, deg_in, hs_a, h0, norm_in, norm_out, hs_b, 0, N, 0);
    prop_kernel<<<pb, 256, 0, stream>>>(esort, offsets, deg_in, hs_b, h0, norm_in, norm_out, hs_a, 0, N, 0);
    prop_kernel<<<pb, 256, 0, stream>>>(esort, offsets, deg_in, hs_a, h0, norm_in, norm_out, 0, out, N, 1);
}